// Round 10
// baseline (114.507 us; speedup 1.0000x reference)
//
#include <hip/hip_runtime.h>
#include <stdint.h>

typedef _Float16 half8 __attribute__((ext_vector_type(8)));
typedef float floatx4 __attribute__((ext_vector_type(4)));
typedef uint32_t u32x4 __attribute__((ext_vector_type(4)));

#define IF 512
#define NF 512
#define TILE_B 16384
#define B_WS_BYTES ((size_t)72 * 4 * TILE_B)   // 4.5 MB

__device__ __forceinline__ uint32_t swz(uint32_t b) {
  return b ^ (((b >> 7) & 7u) << 4);
}
__device__ __forceinline__ uint32_t pk(float a, float b) {
  return __builtin_bit_cast(uint32_t, __builtin_amdgcn_cvt_pkrtz(a, b));
}

// 8-wide uniform cubic B-spline basis for one x, packed fp16 (verified R5-R9)
__device__ __forceinline__ u32x4 BASIS8(float xv) {
  float u = (xv + 2.2f) * 2.5f;
  float fj = __builtin_floorf(u);
  fj = fminf(fmaxf(fj, 3.0f), 7.0f);
  float t = u - fj;
  float omt = 1.0f - t;
  float t2 = t * t, t3 = t2 * t;
  float w0 = omt * omt * omt * 0.16666666666666666f;
  float w1 = __builtin_fmaf(0.5f, t3, 0.66666666666666666f - t2);
  float w2 = __builtin_fmaf(0.5f, (t2 - t3) + t, 0.16666666666666666f);
  float w3 = t3 * 0.16666666666666666f;
  uint32_t c0 = pk(w0, w1);
  uint32_t c1 = pk(w2, w3);
  int j3 = (int)fj - 3;
  int sh = j3 << 4;
  uint64_t w = (uint64_t)c0 | ((uint64_t)c1 << 32);
  uint64_t lo = (sh < 64) ? (w << sh) : 0ull;
  uint64_t hi = (sh == 0) ? 0ull : ((sh < 64) ? (w >> (64 - sh)) : w);
  u32x4 r;
  r.x = (uint32_t)lo; r.y = (uint32_t)(lo >> 32);
  r.z = (uint32_t)hi; r.w = (uint32_t)(hi >> 32);
  return r;
}

__global__ __launch_bounds__(256)
void kan_zero(float4* __restrict__ p, int n4) {
  const int stride = gridDim.x * 256;
  for (int i = blockIdx.x * 256 + threadIdx.x; i < n4; i += stride)
    p[i] = (float4){0.f, 0.f, 0.f, 0.f};
}

// prepass B: weights -> fp16 128x64 tile images, pre-swizzled (R5-verified)
__global__ __launch_bounds__(256)
void kan_prepB(const float* __restrict__ bwg, const float* __restrict__ swg,
               uint8_t* __restrict__ wsB)
{
  const int gid = blockIdx.x * 256 + threadIdx.x;
  const int T = gid >> 10;
  const int q = gid & 1023;
  const int kt = T >> 2;
  const int nt = T & 3;
  const uint32_t p = swz((uint32_t)q * 16u);
  const int row = p >> 7;
  const int c   = (p & 127) >> 1;
  const int n = nt * 128 + row;
  const float* src = (kt < 8) ? bwg + (size_t)n * IF + kt * 64 + c
                              : swg + (size_t)n * 4096 + (kt - 8) * 64 + c;
  float4 f0 = ((const float4*)src)[0];
  float4 f1 = ((const float4*)src)[1];
  u32x4 v; v.x = pk(f0.x, f0.y); v.y = pk(f0.z, f0.w);
           v.z = pk(f1.x, f1.y); v.w = pk(f1.z, f1.w);
  *(u32x4*)(wsB + (size_t)T * TILE_B + (size_t)q * 16) = v;
}

// prepass xT: xT[i][b] = x[b][i]  (LDS-tiled 64x64 transpose, fp32)
__global__ __launch_bounds__(256)
void kan_xT(const float* __restrict__ xg, float* __restrict__ xTg)
{
  __shared__ float t[64][65];
  const int bi = blockIdx.x & 7;        // i-tile
  const int bb = blockIdx.x >> 3;       // b-tile
  const int li = threadIdx.x & 63, lr = threadIdx.x >> 6;
#pragma unroll
  for (int r = 0; r < 64; r += 4)
    t[r + lr][li] = xg[(size_t)(bb * 64 + r + lr) * IF + bi * 64 + li];
  __syncthreads();
#pragma unroll
  for (int r = 0; r < 64; r += 4)
    xTg[(size_t)(bi * 64 + r + lr) * 8192 + bb * 64 + li] = t[li][r + lr];
}

// ---- main: B via LDS dbuf gload_lds; A entirely in registers ----
// block = 256 rows x 128 cols, 8 waves of 64x64 (wm=wv>>1, wn=wv&1), grid 256.
#define STAGE(kt, nb) do { \
    const uint8_t* sb_ = wsB + (size_t)((kt) * 4 + ntI) * TILE_B + (size_t)tid * 16; \
    char* db_ = BsB + (nb) * TILE_B + tid * 16; \
    __builtin_amdgcn_global_load_lds((const __attribute__((address_space(1))) uint32_t*)sb_, \
                                     (__attribute__((address_space(3))) uint32_t*)db_, 16, 0, 0); \
    __builtin_amdgcn_global_load_lds((const __attribute__((address_space(1))) uint32_t*)(sb_ + 8192), \
                                     (__attribute__((address_space(3))) uint32_t*)(db_ + 8192), 16, 0, 0); \
  } while (0)

#define XLS(kt, xs) do { \
    const int i0_ = ((kt) - 8) * 8; \
    _Pragma("unroll") \
    for (int mi = 0; mi < 4; ++mi) \
      _Pragma("unroll") \
      for (int kk = 0; kk < 2; ++kk) \
        xs[mi * 2 + kk] = xTg[(size_t)(i0_ + kk * 4 + hi) * 8192 + rowbase + mi * 16]; \
  } while (0)

#define MAKEAS(xs, aF) do { \
    _Pragma("unroll") \
    for (int q = 0; q < 8; ++q) aF[q] = BASIS8(xs[q]); \
  } while (0)

#define XLB(kt, xf) do { \
    _Pragma("unroll") \
    for (int mi = 0; mi < 4; ++mi) \
      _Pragma("unroll") \
      for (int kk = 0; kk < 2; ++kk) { \
        const float* s_ = xg + (size_t)(rowbase + mi * 16) * IF + (kt) * 64 + kk * 32 + hi * 8; \
        xf[(mi * 2 + kk) * 2]     = ((const float4*)s_)[0]; \
        xf[(mi * 2 + kk) * 2 + 1] = ((const float4*)s_)[1]; \
      } \
  } while (0)

#define MAKEAB(xf, aF) do { \
    _Pragma("unroll") \
    for (int q = 0; q < 8; ++q) { \
      u32x4 v_; \
      v_.x = pk(xf[q * 2].x, xf[q * 2].y);     v_.y = pk(xf[q * 2].z, xf[q * 2].w); \
      v_.z = pk(xf[q * 2 + 1].x, xf[q * 2 + 1].y); v_.w = pk(xf[q * 2 + 1].z, xf[q * 2 + 1].w); \
      aF[q] = v_; \
    } \
  } while (0)

#define COMPUTE(cb, aF) do { \
    _Pragma("unroll") \
    for (int kk = 0; kk < 2; ++kk) { \
      u32x4 bF[4]; \
      _Pragma("unroll") \
      for (int ni = 0; ni < 4; ++ni) \
        bF[ni] = *(const u32x4*)(BsB + (cb) * TILE_B + (rdB[ni] ^ (uint32_t)(kk * 64))); \
      _Pragma("unroll") \
      for (int mi = 0; mi < 4; ++mi) \
        _Pragma("unroll") \
        for (int ni = 0; ni < 4; ++ni) \
          acc[mi][ni] = __builtin_amdgcn_mfma_f32_16x16x32_f16( \
              __builtin_bit_cast(half8, aF[mi * 2 + kk]), \
              __builtin_bit_cast(half8, bF[ni]), acc[mi][ni], 0, 0, 0); \
    } \
  } while (0)

__global__ __launch_bounds__(512, 2)
void kan_gemm(const float* __restrict__ xg, const float* __restrict__ xTg,
              const uint8_t* __restrict__ wsB, float* __restrict__ outg)
{
  __shared__ _Float16 Bs[2][8192];
  char* BsB = (char*)Bs;

  const int tid = threadIdx.x, lane = tid & 63, wv = tid >> 6;
  const int wm = wv >> 1, wn = wv & 1;
  const int rr = lane & 15, hi = lane >> 4;

  // XCD x owns mt in [x*4, x*4+4): A rows L2-resident per XCD
  const int bid = blockIdx.x;
  const int x = bid & 7, j = bid >> 3;
  const int kz  = j & 1;
  const int ntI = (j >> 1) & 3;
  const int mt  = x * 4 + (j >> 3);
  const int brow0 = mt * 256;
  const int bn0 = ntI * 128;
  const int kt0 = kz * 36;
  const int rowbase = brow0 + wm * 64 + rr;

  uint32_t rdB[4];
#pragma unroll
  for (int ni = 0; ni < 4; ++ni)
    rdB[ni] = swz((uint32_t)(wn * 64 + ni * 16 + rr) * 128u + (uint32_t)hi * 16u);

  floatx4 acc[4][4];
#pragma unroll
  for (int mi = 0; mi < 4; ++mi)
#pragma unroll
    for (int ni = 0; ni < 4; ++ni)
      acc[mi][ni] = (floatx4){0.f, 0.f, 0.f, 0.f};

  u32x4 aF0[8], aF1[8];
  float xs0[8], xs1[8];

  STAGE(kt0, 0);

  if (kz == 0) {
    float4 xf[16];
    XLB(0, xf); MAKEAB(xf, aF0);
    __syncthreads();
#pragma unroll 1
    for (int t = 0; t < 8; t += 2) {
      STAGE(t + 1, 1);
      if (t + 1 < 8) XLB(t + 1, xf);
      COMPUTE(0, aF0);
      if (t + 1 < 8) MAKEAB(xf, aF1);
      __syncthreads();
      STAGE(t + 2, 0);                 // t=6 stages kt=8 (first spline tile)
      if (t + 2 < 8) XLB(t + 2, xf);
      COMPUTE(1, aF1);
      if (t + 2 < 8) MAKEAB(xf, aF0);
      __syncthreads();
    }
    XLS(8, xs0); MAKEAS(xs0, aF0);     // buf0 already holds kt=8
  } else {
    XLS(36, xs0); MAKEAS(xs0, aF0);
    __syncthreads();
  }

  const int sBeg = kz ? 36 : 8;
  const int s1 = kt0 + 36;
#pragma unroll 1
  for (int kt = sBeg; kt < s1; kt += 2) {
    STAGE(kt + 1, 1); XLS(kt + 1, xs1);
    COMPUTE(0, aF0);
    MAKEAS(xs1, aF1);                  // VALU overlaps MFMA drain
    __syncthreads();
    const bool more = (kt + 2) < s1;
    if (more) { STAGE(kt + 2, 0); XLS(kt + 2, xs0); }
    COMPUTE(1, aF1);
    if (more) MAKEAS(xs0, aF0);
    __syncthreads();
  }

  // epilogue: C/D col=lane&15, row=(lane>>4)*4+e ; split-K atomic accumulate
  const int er = hi * 4, ec = rr;
#pragma unroll
  for (int mi = 0; mi < 4; ++mi)
#pragma unroll
    for (int ni = 0; ni < 4; ++ni) {
      const size_t base = (size_t)(brow0 + wm * 64 + mi * 16 + er) * NF
                        + (size_t)(bn0 + wn * 64 + ni * 16 + ec);
#pragma unroll
      for (int e = 0; e < 4; ++e)
        unsafeAtomicAdd(outg + base + (size_t)e * NF, acc[mi][ni][e]);
    }
}

extern "C" void kernel_launch(void* const* d_in, const int* in_sizes, int n_in,
                              void* d_out, int out_size, void* d_ws, size_t ws_size,
                              hipStream_t stream) {
  const float* x  = (const float*)d_in[0];
  const float* bw = (const float*)d_in[1];
  const float* sw = (const float*)d_in[2];
  float* out = (float*)d_out;
  uint8_t* wsB = (uint8_t*)d_ws;                 // 4.5 MB
  float*   xT  = (float*)(wsB + B_WS_BYTES);     // 16 MB

  hipLaunchKernelGGL(kan_zero,  dim3(2048), dim3(256), 0, stream, (float4*)out, out_size / 4);
  hipLaunchKernelGGL(kan_prepB, dim3(1152), dim3(256), 0, stream, bw, sw, wsB);
  hipLaunchKernelGGL(kan_xT,    dim3(1024), dim3(256), 0, stream, x, xT);
  hipLaunchKernelGGL(kan_gemm,  dim3(256),  dim3(512), 0, stream, x, xT, wsB, out);
}

// Round 11
// 92.920 us; speedup vs baseline: 1.2323x; 1.2323x over previous
//
#include <hip/hip_runtime.h>
#include <stdint.h>

typedef _Float16 half8 __attribute__((ext_vector_type(8)));
typedef float floatx4 __attribute__((ext_vector_type(4)));
typedef uint32_t u32x4 __attribute__((ext_vector_type(4)));

#define IF 512
#define NF 512
#define TILE_BYTES 16384
#define B_WS_BYTES ((size_t)72 * 4 * TILE_BYTES)    // 4.5 MB
#define XA_WS_BYTES ((size_t)64 * 8 * TILE_BYTES)   // 8 MB

__device__ __forceinline__ uint32_t swz(uint32_t b) {
  return b ^ (((b >> 7) & 7u) << 4);
}
__device__ __forceinline__ uint32_t pk(float a, float b) {
  return __builtin_bit_cast(uint32_t, __builtin_amdgcn_cvt_pkrtz(a, b));
}

// 8-wide uniform cubic B-spline basis for one x, packed fp16 (verified R5-R10)
__device__ __forceinline__ u32x4 BASIS8(float xv) {
  float u = (xv + 2.2f) * 2.5f;
  float fj = __builtin_floorf(u);
  fj = fminf(fmaxf(fj, 3.0f), 7.0f);
  float t = u - fj;
  float omt = 1.0f - t;
  float t2 = t * t, t3 = t2 * t;
  float w0 = omt * omt * omt * 0.16666666666666666f;
  float w1 = __builtin_fmaf(0.5f, t3, 0.66666666666666666f - t2);
  float w2 = __builtin_fmaf(0.5f, (t2 - t3) + t, 0.16666666666666666f);
  float w3 = t3 * 0.16666666666666666f;
  uint32_t c0 = pk(w0, w1);
  uint32_t c1 = pk(w2, w3);
  int j3 = (int)fj - 3;
  int sh = j3 << 4;
  uint64_t w = (uint64_t)c0 | ((uint64_t)c1 << 32);
  uint64_t lo = (sh < 64) ? (w << sh) : 0ull;
  uint64_t hi = (sh == 0) ? 0ull : ((sh < 64) ? (w >> (64 - sh)) : w);
  u32x4 r;
  r.x = (uint32_t)lo; r.y = (uint32_t)(lo >> 32);
  r.z = (uint32_t)hi; r.w = (uint32_t)(hi >> 32);
  return r;
}

__global__ __launch_bounds__(256)
void kan_zero(float4* __restrict__ p, int n4) {
  const int stride = gridDim.x * 256;
  for (int i = blockIdx.x * 256 + threadIdx.x; i < n4; i += stride)
    p[i] = (float4){0.f, 0.f, 0.f, 0.f};
}

// prepass B: weights -> fp16 128x64 tile images, pre-swizzled (R5-verified)
__global__ __launch_bounds__(256)
void kan_prepB(const float* __restrict__ bwg, const float* __restrict__ swg,
               uint8_t* __restrict__ wsB)
{
  const int gid = blockIdx.x * 256 + threadIdx.x;
  const int T = gid >> 10;          // tile kt*4+nt
  const int q = gid & 1023;
  const int kt = T >> 2;
  const int nt = T & 3;
  const uint32_t p = swz((uint32_t)q * 16u);
  const int row = p >> 7;
  const int c   = (p & 127) >> 1;
  const int n = nt * 128 + row;
  const float* src = (kt < 8) ? bwg + (size_t)n * IF + kt * 64 + c
                              : swg + (size_t)n * 4096 + (kt - 8) * 64 + c;
  float4 f0 = ((const float4*)src)[0];
  float4 f1 = ((const float4*)src)[1];
  u32x4 v; v.x = pk(f0.x, f0.y); v.y = pk(f0.z, f0.w);
           v.z = pk(f1.x, f1.y); v.w = pk(f1.z, f1.w);
  *(u32x4*)(wsB + (size_t)T * TILE_BYTES + (size_t)q * 16) = v;
}

// prepass XA: x -> fp16 128x64 tile images (base-phase A), pre-swizzled
__global__ __launch_bounds__(256)
void kan_prepXA(const float* __restrict__ xg, uint8_t* __restrict__ wsXA)
{
  const int gid = blockIdx.x * 256 + threadIdx.x;   // 512K chunks
  const int T = gid >> 10;          // tile mt*8+kt
  const int q = gid & 1023;
  const int mt = T >> 3;
  const int kt = T & 7;
  const uint32_t p = swz((uint32_t)q * 16u);
  const int row = p >> 7;
  const int c   = (p & 127) >> 1;
  const float* src = xg + (size_t)(mt * 128 + row) * IF + kt * 64 + c;
  float4 f0 = ((const float4*)src)[0];
  float4 f1 = ((const float4*)src)[1];
  u32x4 v; v.x = pk(f0.x, f0.y); v.y = pk(f0.z, f0.w);
           v.z = pk(f1.x, f1.y); v.w = pk(f1.z, f1.w);
  *(u32x4*)(wsXA + (size_t)T * TILE_BYTES + (size_t)q * 16) = v;
}

// ---- main: fused GEMM. 4 waves of 64x64, 1 barrier/step, split-K=2 ----
__global__ __launch_bounds__(256, 2)
void kan_gemm(const float* __restrict__ xg, const uint8_t* __restrict__ wsB,
              const uint8_t* __restrict__ wsXA, float* __restrict__ outg)
{
  __shared__ _Float16 As[2][8192];
  __shared__ _Float16 Bs[2][8192];
  char* AsB = (char*)As;
  char* BsB = (char*)Bs;

  const int tid = threadIdx.x, lane = tid & 63, wv = tid >> 6;
  const int wm = wv >> 1, wn = wv & 1;          // 2x2 wave grid, 64x64 tiles
  const int rr = lane & 15, hi = lane >> 4;

  // 512 blocks = 8 XCD x 64; XCD owns mt in [x*8, x*8+8) (A L2-resident)
  const int bid = blockIdx.x;
  const int x = bid & 7, j = bid >> 3;
  const int kz  = j & 1;
  const int ntI = (j >> 1) & 3;
  const int mt  = x * 8 + (j >> 3);
  const int bm0 = mt * 128, bn0 = ntI * 128;
  const int kt0 = kz * 36, kt1 = kt0 + 36;

  // A-staging decode (spline): thread owns row rT, i-locals il..il+3
  const int rT = tid >> 1;
  const int il = (tid & 1) * 4;
  uint32_t wA[4];
#pragma unroll
  for (int jj = 0; jj < 4; ++jj)
    wA[jj] = swz((uint32_t)rT * 128u + (uint32_t)(il + jj) * 16u);

  uint32_t rdA[4], rdB[4];
#pragma unroll
  for (int mi = 0; mi < 4; ++mi)
    rdA[mi] = swz((uint32_t)(wm * 64 + mi * 16 + rr) * 128u + (uint32_t)hi * 16u);
#pragma unroll
  for (int ni = 0; ni < 4; ++ni)
    rdB[ni] = swz((uint32_t)(wn * 64 + ni * 16 + rr) * 128u + (uint32_t)hi * 16u);

  floatx4 acc[4][4];
#pragma unroll
  for (int mi = 0; mi < 4; ++mi)
#pragma unroll
    for (int ni = 0; ni < 4; ++ni)
      acc[mi][ni] = (floatx4){0.f, 0.f, 0.f, 0.f};

  auto STAGE_B = [&](int kt, int nb) {
    const uint8_t* s = wsB + (size_t)(kt * 4 + ntI) * TILE_BYTES + (size_t)tid * 16;
    char* d = BsB + nb * TILE_BYTES + tid * 16;
#pragma unroll
    for (int q = 0; q < 4; ++q)
      __builtin_amdgcn_global_load_lds(
          (const __attribute__((address_space(1))) uint32_t*)(s + q * 4096),
          (__attribute__((address_space(3))) uint32_t*)(d + q * 4096), 16, 0, 0);
  };
  auto STAGE_AI = [&](int kt, int nb) {   // base tiles from x-image
    const uint8_t* s = wsXA + (size_t)(mt * 8 + kt) * TILE_BYTES + (size_t)tid * 16;
    char* d = AsB + nb * TILE_BYTES + tid * 16;
#pragma unroll
    for (int q = 0; q < 4; ++q)
      __builtin_amdgcn_global_load_lds(
          (const __attribute__((address_space(1))) uint32_t*)(s + q * 4096),
          (__attribute__((address_space(3))) uint32_t*)(d + q * 4096), 16, 0, 0);
  };
  auto XL = [&](int kt) -> float4 {       // spline x quad for this thread
    return *(const float4*)(xg + (size_t)(bm0 + rT) * IF + (kt - 8) * 8 + il);
  };
  auto WRITEA = [&](float4 xq, int nb) {  // 4 BASIS8 + 4 swizzled ds_write_b128
    char* base = AsB + nb * TILE_BYTES;
    *(u32x4*)(base + wA[0]) = BASIS8(xq.x);
    *(u32x4*)(base + wA[1]) = BASIS8(xq.y);
    *(u32x4*)(base + wA[2]) = BASIS8(xq.z);
    *(u32x4*)(base + wA[3]) = BASIS8(xq.w);
  };
  auto COMPUTE = [&](int cb) {
    const char* ab = AsB + cb * TILE_BYTES;
    const char* bb = BsB + cb * TILE_BYTES;
#pragma unroll
    for (int kk = 0; kk < 2; ++kk) {
      const uint32_t ko = (uint32_t)(kk * 64);
      half8 a[4], b[4];
#pragma unroll
      for (int mi = 0; mi < 4; ++mi)
        a[mi] = *(const half8*)(ab + (rdA[mi] ^ ko));   // XOR: swizzle-safe
#pragma unroll
      for (int ni = 0; ni < 4; ++ni)
        b[ni] = *(const half8*)(bb + (rdB[ni] ^ ko));
#pragma unroll
      for (int mi = 0; mi < 4; ++mi)
#pragma unroll
        for (int ni = 0; ni < 4; ++ni)
          acc[mi][ni] = __builtin_amdgcn_mfma_f32_16x16x32_f16(a[mi], b[ni], acc[mi][ni], 0, 0, 0);
    }
  };

  // prologue: fill buffer 0 with tile kt0
  STAGE_B(kt0, 0);
  if (kz == 0) {
    STAGE_AI(0, 0);
  } else {
    float4 xq = XL(kt0);
    WRITEA(xq, 0);
  }
  __syncthreads();

#pragma unroll 1
  for (int kt = kt0; kt < kt1; ++kt) {
    const int cur = (kt - kt0) & 1;
    const int nxt = cur ^ 1;
    const bool more = (kt + 1) < kt1;
    float4 xq;
    bool spl = false;
    if (more) {
      STAGE_B(kt + 1, nxt);                 // async DMA, overlaps COMPUTE
      if (kt + 1 < 8) STAGE_AI(kt + 1, nxt);
      else { xq = XL(kt + 1); spl = true; } // issue x loads early
    }
    COMPUTE(cur);                           // 16 ds_read + 32 MFMA
    if (spl) WRITEA(xq, nxt);               // basis VALU + ds_write after MFMA
    __syncthreads();                        // single drain per step
  }

  // epilogue: C/D col=lane&15, row=(lane>>4)*4+e ; split-K atomic accumulate
  const int er = hi * 4, ec = rr;
#pragma unroll
  for (int mi = 0; mi < 4; ++mi)
#pragma unroll
    for (int ni = 0; ni < 4; ++ni) {
      const size_t base = (size_t)(bm0 + wm * 64 + mi * 16 + er) * NF
                        + (size_t)(bn0 + wn * 64 + ni * 16 + ec);
#pragma unroll
      for (int e = 0; e < 4; ++e)
        unsafeAtomicAdd(outg + base + (size_t)e * NF, acc[mi][ni][e]);
    }
}

extern "C" void kernel_launch(void* const* d_in, const int* in_sizes, int n_in,
                              void* d_out, int out_size, void* d_ws, size_t ws_size,
                              hipStream_t stream) {
  const float* x  = (const float*)d_in[0];
  const float* bw = (const float*)d_in[1];
  const float* sw = (const float*)d_in[2];
  float* out = (float*)d_out;
  uint8_t* wsB  = (uint8_t*)d_ws;            // 4.5 MB
  uint8_t* wsXA = wsB + B_WS_BYTES;          // 8 MB (total 12.5 MB, fits per R7)

  hipLaunchKernelGGL(kan_zero,   dim3(2048), dim3(256), 0, stream, (float4*)out, out_size / 4);
  hipLaunchKernelGGL(kan_prepB,  dim3(1152), dim3(256), 0, stream, bw, sw, wsB);
  hipLaunchKernelGGL(kan_prepXA, dim3(2048), dim3(256), 0, stream, x, wsXA);
  hipLaunchKernelGGL(kan_gemm,   dim3(512),  dim3(256), 0, stream, x, wsB, wsXA, out);
}